// Round 1
// baseline (5058.627 us; speedup 1.0000x reference)
//
#include <hip/hip_runtime.h>
#include <cstdint>

#define TT 128   // time steps (= bucket_size)
#define BB 128   // batch
#define II 512   // input dim
#define HH 512   // hidden dim
#define DD 1024  // I + H
#define NC 513   // H + 1
#define NPAD 520 // row pitch for lnXW / vbuf (bf16)
#define NT 36    // n-tiles of 16 in big GEMM (576 padded cols)
#define NT2 33   // n-tiles of 16 in recurrence GEMV (528 padded cols, col 512 = tile 32)
#define EPSL 1e-5f

typedef short    s8v __attribute__((ext_vector_type(8)));
typedef _Float16 h8v __attribute__((ext_vector_type(8)));
typedef float    f4v __attribute__((ext_vector_type(4)));

__device__ __forceinline__ ushort f2bf(float f){
  uint u = __builtin_bit_cast(uint, f);
  uint r = (u + 0x7fffu + ((u >> 16) & 1u)) >> 16;
  return (ushort)r;
}
__device__ __forceinline__ float bf2f(ushort s){
  uint u = ((uint)s) << 16;
  return __builtin_bit_cast(float, u);
}
__device__ __forceinline__ float hsig(float x){
  return fminf(fmaxf(0.2f * x + 0.5f, 0.f), 1.f);
}

// ---------------- pre-pack W / U into MFMA B-fragment order (bf16, big GEMM) ----
// dst element idx = ((kc*NT + nt)*16 + ni)*8 + kl  holds  src[k=kc*8+kl][n=nt*16+ni]
__global__ void prepack_B(const float* __restrict__ src, ushort* __restrict__ dst){
  int idx = blockIdx.x * 256 + threadIdx.x;
  if (idx >= 128 * NT * 16 * 8) return;
  int kl = idx & 7;
  int ni = (idx >> 3) & 15;
  int nt = (idx >> 7) % NT;
  int kc = idx / (NT * 16 * 8);
  int k = kc * 8 + kl;
  int n = nt * 16 + ni;
  float v = (n < NC) ? src[k * NC + n] : 0.f;
  dst[idx] = f2bf(v);
}

// ---------------- pre-pack U_hi (rows I..I+511) in f16 B-fragment order ---------
// dst idx = ((kc*NT2 + nt)*16 + ni)*8 + kl holds f16(U[II + kc*8 + kl][nt*16 + ni])
__global__ void prepack_Uhi_f16(const float* __restrict__ U, ushort* __restrict__ dst){
  int idx = blockIdx.x * 256 + threadIdx.x;
  if (idx >= 64 * NT2 * 16 * 8) return;
  int kl = idx & 7;
  int ni = (idx >> 3) & 15;
  int nt = (idx >> 7) % NT2;
  int kc = idx / (NT2 * 16 * 8);
  int k = II + kc * 8 + kl;
  int n = nt * 16 + ni;
  float v = (n < NC) ? U[(size_t)k * NC + n] : 0.f;
  _Float16 h = (_Float16)v;
  dst[idx] = __builtin_bit_cast(ushort, h);
}

// ---------------- fused GEMM (+ optional row-LayerNorm) -------------------
__global__ __launch_bounds__(1024) void gemm_ln(
    const float* __restrict__ A, int amode, int ksteps,
    const ushort* __restrict__ Bpk, ushort* __restrict__ out,
    int do_ln, const float* __restrict__ gam, const float* __restrict__ bet,
    const float* __restrict__ bias)
{
  __shared__ ushort As[64][40];
  __shared__ float red[4][4][16][2];
  int tid = threadIdx.x;
  int lane = tid & 63, wid = tid >> 6;
  int quad = lane >> 4, l16 = lane & 15;
  int wm = wid >> 2, wn = wid & 3;
  int blk = blockIdx.x;

  f4v acc[9];
#pragma unroll
  for (int i = 0; i < 9; i++) acc[i] = (f4v){0.f, 0.f, 0.f, 0.f};

  int arow = tid >> 4;
  int acp  = tid & 15;
  int r = blk * 64 + arow;
  const float* aptr;
  if (amode == 0){ int t = r >> 7, b = r & 127; aptr = A + ((size_t)(b * TT + t)) * II + acp * 2; }
  else           { aptr = A + (size_t)r * DD + acp * 2; }

  for (int ks = 0; ks < ksteps; ks++){
    __syncthreads();
    float2 a2 = *(const float2*)(aptr + ks * 32);
    uint pk = (uint)f2bf(a2.x) | ((uint)f2bf(a2.y) << 16);
    *(uint*)&As[arow][acp * 2] = pk;
    __syncthreads();
    s8v af = *(const s8v*)&As[wm * 16 + l16][quad * 8];
    int kc = ks * 4 + quad;
    const s8v* bp = (const s8v*)Bpk + (size_t)kc * (NT * 16) + l16;
#pragma unroll
    for (int i = 0; i < 9; i++){
      s8v bf = bp[(wn * 9 + i) * 16];
      acc[i] = __builtin_amdgcn_mfma_f32_16x16x32_bf16(af, bf, acc[i], 0, 0, 0);
    }
  }

  int rowbase = blk * 64 + wm * 16 + quad * 4;
  if (do_ln){
    float s1[4], s2[4];
#pragma unroll
    for (int g = 0; g < 4; g++){
      float a = 0.f, q = 0.f;
#pragma unroll
      for (int i = 0; i < 9; i++){ float v = acc[i][g]; a += v; q += v * v; }
#pragma unroll
      for (int m = 1; m < 16; m <<= 1){ a += __shfl_xor(a, m, 64); q += __shfl_xor(q, m, 64); }
      s1[g] = a; s2[g] = q;
    }
    if (l16 == 0){
#pragma unroll
      for (int g = 0; g < 4; g++){
        red[wm][wn][quad * 4 + g][0] = s1[g];
        red[wm][wn][quad * 4 + g][1] = s2[g];
      }
    }
    __syncthreads();
#pragma unroll
    for (int g = 0; g < 4; g++){
      int rr = quad * 4 + g;
      float S1 = red[wm][0][rr][0] + red[wm][1][rr][0] + red[wm][2][rr][0] + red[wm][3][rr][0];
      float S2 = red[wm][0][rr][1] + red[wm][1][rr][1] + red[wm][2][rr][1] + red[wm][3][rr][1];
      float mean = S1 * (1.f / 513.f);
      float var  = S2 * (1.f / 513.f) - mean * mean;
      float inv  = 1.f / (sqrtf(var + EPSL) + EPSL);
      size_t rg = (size_t)(rowbase + g);
#pragma unroll
      for (int i = 0; i < 9; i++){
        int n = wn * 144 + i * 16 + l16;
        if (n < NC){
          float val = gam[n] * ((acc[i][g] - mean) * inv) + bet[n] + bias[n];
          out[rg * NPAD + n] = f2bf(val);
        }
      }
    }
  } else {
#pragma unroll
    for (int g = 0; g < 4; g++){
      size_t rg = (size_t)(rowbase + g);
#pragma unroll
      for (int i = 0; i < 9; i++){
        int n = wn * 144 + i * 16 + l16;
        if (n < NC) out[rg * NPAD + n] = f2bf(acc[i][g]);
      }
    }
  }
}

// ---------------- per-batch-row sequential recurrence ----------------------
// one block per batch row b; 512 threads; thread n owns column n of v/h.
// Per step: 3 barriers. GEMV y = tanh . U_hi done on the matrix pipe:
// tanh broadcast into all 16 A-rows of mfma_f32_16x16x32_f16 -> every lane's
// acc[quad][*] holds y[its own column]. Col 512 = n-tile 32 (wave 7 extra).
__global__ __launch_bounds__(512) void rnn_layer(
    int layer,
    const float* __restrict__ x,
    float* __restrict__ h_seq,
    const ushort* __restrict__ lnXW,
    ushort* __restrict__ vbuf,
    float* __restrict__ fkbuf,
    float* __restrict__ hvbuf,
    const ushort* __restrict__ Upk2,
    const int* __restrict__ mask,
    const float* __restrict__ gam1, const float* __restrict__ bet1,
    const float* __restrict__ bias,
    float* __restrict__ out)
{
  __shared__ __align__(16) ushort tanh16[512];  // f16 tanh (GEMV A operand)
  __shared__ __align__(16) float  tanhvf[512];  // f32 tanh (h update)
  __shared__ float red_a[8], red_q[8];
  __shared__ float sh_v0, sh_v512, sh_y512;

  int tid = threadIdx.x;
  int b = blockIdx.x;
  int lane = tid & 63, wid = tid >> 6;
  int quad = lane >> 4, l16 = lane & 15;
  const bool lastL = (layer == 3);

  float sv = 0.f, v512 = 0.f;          // v512 only meaningful on tid 0
  float h_lo = 0.f, h_hi = 0.f;
  float fk_c = 0.f, hv_c = 0.f;        // gate carries, duplicated on all threads
  float g1n = gam1[tid], b1n = bet1[tid];
  float g10 = gam1[0],   b10 = bet1[0];
  float g1e = gam1[512], b1e = bet1[512];
  float bias0 = bias[0];
  // previous-step gates for the deferred col-512 update (kept by all, used by tid 0)
  float ho_p = 0.f, xo_p = 0.f, bo_p = 0.f, xu5_p = 0.f;
  int mk_p = 0;

  if (lane == 0){ red_a[wid] = 0.f; red_q[wid] = 0.f; }
  if (tid == 0){ sh_v0 = 0.f; sh_v512 = 0.f; sh_y512 = 0.f; }

  for (int t = 0; t < TT; t++){
    size_t row = (size_t)(t * BB + b);
    __syncthreads();   // step start: prev-step red_*, sh_v0, sh_y512 visible

    // ---- A0: issue this-step loads; tid0: deferred col-512 state update
    int   mraw  = mask[b * TT + t];
    int   mprev = (t > 0) ? mask[b * TT + t - 1] : 0;
    float lw    = bf2f(lnXW[row * NPAD + tid]);
    float lw0   = bf2f(lnXW[row * NPAD]);
    float lw512 = bf2f(lnXW[row * NPAD + 512]);
    float xu    = bf2f(vbuf[row * NPAD + tid]);
    float xlo, xhi;
    if (layer == 0){ xlo = x[((size_t)(b * TT + t)) * II + tid]; xhi = 0.f; }
    else { xlo = h_seq[row * DD + tid]; xhi = h_seq[row * DD + 512 + tid]; }
    float fkp_tm1, fkp, hvp;
    if (layer == 0){ fkp_tm1 = 0.f; fkp = 0.f; hvp = 1.f; }
    else {
      fkp_tm1 = fkbuf[t * BB + b];
      fkp = (t + 1 < TT) ? fkbuf[(t + 1) * BB + b] : 0.f;
      hvp = hvbuf[t * BB + b];
    }
    if (tid == 0){
      if (t > 0){
        float nv5 = ho_p * v512 + xo_p * xu5_p + bo_p * sh_y512;
        if (mk_p) v512 = nv5;
        if (!lastL) vbuf[(row - BB) * NPAD + 512] = f2bf(v512);
      }
      sh_v512 = v512;
    }
    __syncthreads();   // sync2: sh_v512 visible

    // ---- A2: LN stats + gate scalars (all threads, redundant & identical)
    float S = red_a[0] + red_a[1] + red_a[2] + red_a[3]
            + red_a[4] + red_a[5] + red_a[6] + red_a[7];
    float Q = red_q[0] + red_q[1] + red_q[2] + red_q[3]
            + red_q[4] + red_q[5] + red_q[6] + red_q[7];
    float vv5 = sh_v512;
    S += vv5; Q += vv5 * vv5;
    float v0 = sh_v0;
    float mean = S * (1.f / 513.f);
    float var  = Q * (1.f / 513.f) - mean * mean;
    float inv  = 1.f / (sqrtf(var + EPSL) + EPSL);

    bool mk  = mraw > 0;
    bool mk2 = (t > 0) && (mprev > 0) && !mk;
    float sum20 = (v0 - mean) * inv * g10 + b10;
    float s0 = lw0 + sum20;
    float fk_both = hsig(s0);
    float fk_t1   = hsig(sum20 + bias0);
    float fk = fkp_tm1 + (1.f - fkp_tm1) * (fk_c * fk_both + (1.f - fk_c) * fk_t1);
    if (mk2) fk = 0.f;
    float h_only = hv_c * fk * (fkp + (1.f - fkp) * (1.f - hvp));
    float x_only = hvp * (1.f - fkp) * (1.f - fk + fk * (1.f - hv_c));
    float both   = (1.f - fkp) * fk * hv_c * hvp;
    float hv = 1.f - (1.f - h_only) * (1.f - x_only) * (1.f - both);
    float fk_new = mk ? fk : fk_c;
    float hv_new = mk ? hv : hv_c;
    if (mk2) fk_new = 0.f;
    fk_c = fk_new; hv_c = hv_new;
    if (tid == 0 && !lastL){
      fkbuf[t * BB + b] = fk_new;
      hvbuf[t * BB + b] = hv_new;
    }

    // ---- B: LN apply + tanh; publish tanh in f16 (GEMV) and f32 (h update)
    float sum2 = (sv - mean) * inv * g1n + b1n;
    float s = lw + sum2;
    float th = tanhf(s);
    if (tid == 0){
      float sum2e = (vv5 - mean) * inv * g1e + b1e;
      float se = lw512 + sum2e;
      float the = tanhf(se);
      tanh16[511] = __builtin_bit_cast(ushort, (_Float16)the);
      tanhvf[511] = the;
    } else {
      tanh16[tid - 1] = __builtin_bit_cast(ushort, (_Float16)th);
      tanhvf[tid - 1] = th;
    }
    __syncthreads();   // sync3: tanh visible

    // ---- C: GEMV on the matrix pipe. Wave w -> n-tiles 4w..4w+3 (cols 64w..64w+63);
    //         wave 7 additionally does tile 32 (col 512).
    f4v a0 = (f4v){0.f,0.f,0.f,0.f}, a1 = a0, a2 = a0, a3 = a0, a4 = a0;
    const h8v* Uf = (const h8v*)Upk2;
    int cbase = wid * 4;
#pragma unroll
    for (int ks = 0; ks < 16; ks++){
      h8v af = *(const h8v*)&tanh16[ks * 32 + quad * 8];   // broadcast: all 16 A-rows equal
      const h8v* bp = Uf + ((size_t)(ks * 4 + quad) * NT2 + cbase) * 16 + l16;
      a0 = __builtin_amdgcn_mfma_f32_16x16x32_f16(af, bp[0],  a0, 0, 0, 0);
      a1 = __builtin_amdgcn_mfma_f32_16x16x32_f16(af, bp[16], a1, 0, 0, 0);
      a2 = __builtin_amdgcn_mfma_f32_16x16x32_f16(af, bp[32], a2, 0, 0, 0);
      a3 = __builtin_amdgcn_mfma_f32_16x16x32_f16(af, bp[48], a3, 0, 0, 0);
      if (wid == 7)
        a4 = __builtin_amdgcn_mfma_f32_16x16x32_f16(af, bp[64], a4, 0, 0, 0);
    }
    float y = a0[0];
    y = (quad == 1) ? a1[0] : y;
    y = (quad == 2) ? a2[0] : y;
    y = (quad == 3) ? a3[0] : y;
    if (wid == 7 && lane == 0) sh_y512 = a4[0];

    // ---- D: state updates, stream writes, next-step LN stats
    float thh = tanhvf[tid];               // tanh(s[tid+1]) = h_core col tid
    float nh_lo = h_only * h_lo + x_only * xlo;
    float nh_hi = h_only * h_hi + x_only * xhi + both * thh;
    if (mk){ h_lo = nh_lo; h_hi = nh_hi; }
    float nv = h_only * sv + x_only * xu + both * y;
    if (mk) sv = nv;
    if (!lastL){
      vbuf[row * NPAD + tid] = f2bf(sv);
      h_seq[row * DD + tid] = h_lo;
      h_seq[row * DD + 512 + tid] = h_hi;
    }
    if (lastL && t == TT - 1) out[b * HH + tid] = h_hi;

    ho_p = h_only; xo_p = x_only; bo_p = both; mk_p = mk ? 1 : 0;
    xu5_p = bf2f(vbuf[row * NPAD + 512]);  // broadcast; consumed by tid0 next step
    if (tid == 0) sh_v0 = sv;

    float a = sv, q = sv * sv;
#pragma unroll
    for (int m = 1; m < 64; m <<= 1){ a += __shfl_xor(a, m, 64); q += __shfl_xor(q, m, 64); }
    if (lane == 0){ red_a[wid] = a; red_q[wid] = q; }
  }

  // epilogue: final col-512 update (t = TT-1), layers 0..2 only
  __syncthreads();
  if (tid == 0 && !lastL){
    float nv5 = ho_p * v512 + xo_p * xu5_p + bo_p * sh_y512;
    if (mk_p) v512 = nv5;
    vbuf[(size_t)((TT - 1) * BB + b) * NPAD + 512] = f2bf(v512);
  }
}

extern "C" void kernel_launch(void* const* d_in, const int* in_sizes, int n_in,
                              void* d_out, int out_size, void* d_ws, size_t ws_size,
                              hipStream_t stream)
{
  (void)in_sizes; (void)n_in; (void)out_size; (void)ws_size;
  const float* x      = (const float*)d_in[0];
  const int*   mask   = (const int*)d_in[1];
  const float* W      = (const float*)d_in[2];
  const float* U      = (const float*)d_in[3];
  const float* bias   = (const float*)d_in[4];
  const float* gammas = (const float*)d_in[5];
  const float* betas  = (const float*)d_in[6];
  float* out = (float*)d_out;

  char* ws = (char*)d_ws;
  size_t off = 0;
  auto alloc = [&](size_t bytes) -> void* {
    void* p = ws + off;
    off += (bytes + 255) & ~(size_t)255;
    return p;
  };
  float*  h_seq = (float*) alloc((size_t)TT * BB * DD * 4);
  ushort* lnXW  = (ushort*)alloc((size_t)TT * BB * NPAD * 2);
  ushort* vbuf  = (ushort*)alloc((size_t)TT * BB * NPAD * 2);
  float*  fkbuf = (float*) alloc((size_t)TT * BB * 4);
  float*  hvbuf = (float*) alloc((size_t)TT * BB * 4);
  ushort* Wpk   = (ushort*)alloc((size_t)128 * NT * 16 * 8 * 2);
  ushort* Upk   = (ushort*)alloc((size_t)128 * NT * 16 * 8 * 2);
  ushort* Upk2  = (ushort*)alloc((size_t)64 * NT2 * 16 * 8 * 2);

  int npk = 128 * NT * 16 * 8;
  prepack_B<<<dim3((npk + 255) / 256), dim3(256), 0, stream>>>(W, Wpk);
  prepack_B<<<dim3((npk + 255) / 256), dim3(256), 0, stream>>>(U, Upk);
  int npk2 = 64 * NT2 * 16 * 8;
  prepack_Uhi_f16<<<dim3((npk2 + 255) / 256), dim3(256), 0, stream>>>(U, Upk2);

  const float* g0 = gammas,      *g1 = gammas + NC;
  const float* be0 = betas,      *be1 = betas + NC;

  // layer 0: lnXW = LN(x @ W_lo)+b ; vbuf = x @ U_lo (raw)
  gemm_ln<<<dim3(256), dim3(1024), 0, stream>>>(x, 0, 16, Wpk, lnXW, 1, g0, be0, bias);
  gemm_ln<<<dim3(256), dim3(1024), 0, stream>>>(x, 0, 16, Upk, vbuf, 0, g0, be0, bias);
  rnn_layer<<<dim3(BB), dim3(512), 0, stream>>>(0, x, h_seq, lnXW, vbuf, fkbuf, hvbuf,
                                                Upk2, mask, g1, be1, bias, out);
  for (int d = 1; d < 4; d++){
    gemm_ln<<<dim3(256), dim3(1024), 0, stream>>>(h_seq, 1, 32, Wpk, lnXW, 1, g0, be0, bias);
    rnn_layer<<<dim3(BB), dim3(512), 0, stream>>>(d, x, h_seq, lnXW, vbuf, fkbuf, hvbuf,
                                                  Upk2, mask, g1, be1, bias, out);
  }
}

// Round 2
// 4437.758 us; speedup vs baseline: 1.1399x; 1.1399x over previous
//
#include <hip/hip_runtime.h>
#include <cstdint>

#define TT 128   // time steps (= bucket_size)
#define BB 128   // batch
#define II 512   // input dim
#define HH 512   // hidden dim
#define DD 1024  // I + H
#define NC 513   // H + 1
#define NPAD 520 // row pitch for lnXW / vbuf (bf16)
#define NT 36    // n-tiles of 16 in big GEMM (576 padded cols)
#define NT2 33   // n-tiles of 16 in recurrence GEMV packing (tile 32 unused now)
#define XST 520  // xch row pitch (floats)
#define EPSL 1e-5f

typedef short    s8v __attribute__((ext_vector_type(8)));
typedef _Float16 h8v __attribute__((ext_vector_type(8)));
typedef float    f4v __attribute__((ext_vector_type(4)));

__device__ __forceinline__ ushort f2bf(float f){
  uint u = __builtin_bit_cast(uint, f);
  uint r = (u + 0x7fffu + ((u >> 16) & 1u)) >> 16;
  return (ushort)r;
}
__device__ __forceinline__ float bf2f(ushort s){
  uint u = ((uint)s) << 16;
  return __builtin_bit_cast(float, u);
}
__device__ __forceinline__ float hsig(float x){
  return fminf(fmaxf(0.2f * x + 0.5f, 0.f), 1.f);
}

// ---------------- pre-pack W / U into MFMA B-fragment order (bf16, big GEMM) ----
// dst element idx = ((kc*NT + nt)*16 + ni)*8 + kl  holds  src[k=kc*8+kl][n=nt*16+ni]
__global__ void prepack_B(const float* __restrict__ src, ushort* __restrict__ dst){
  int idx = blockIdx.x * 256 + threadIdx.x;
  if (idx >= 128 * NT * 16 * 8) return;
  int kl = idx & 7;
  int ni = (idx >> 3) & 15;
  int nt = (idx >> 7) % NT;
  int kc = idx / (NT * 16 * 8);
  int k = kc * 8 + kl;
  int n = nt * 16 + ni;
  float v = (n < NC) ? src[k * NC + n] : 0.f;
  dst[idx] = f2bf(v);
}

// ---------------- pre-pack U_hi (rows I..I+511) in f16 B-fragment order ---------
__global__ void prepack_Uhi_f16(const float* __restrict__ U, ushort* __restrict__ dst){
  int idx = blockIdx.x * 256 + threadIdx.x;
  if (idx >= 64 * NT2 * 16 * 8) return;
  int kl = idx & 7;
  int ni = (idx >> 3) & 15;
  int nt = (idx >> 7) % NT2;
  int kc = idx / (NT2 * 16 * 8);
  int k = II + kc * 8 + kl;
  int n = nt * 16 + ni;
  float v = (n < NC) ? U[(size_t)k * NC + n] : 0.f;
  _Float16 h = (_Float16)v;
  dst[idx] = __builtin_bit_cast(ushort, h);
}

// ---------------- fused GEMM (+ optional row-LayerNorm) -------------------
__global__ __launch_bounds__(1024) void gemm_ln(
    const float* __restrict__ A, int amode, int ksteps,
    const ushort* __restrict__ Bpk, ushort* __restrict__ out,
    int do_ln, const float* __restrict__ gam, const float* __restrict__ bet,
    const float* __restrict__ bias)
{
  __shared__ ushort As[64][40];
  __shared__ float red[4][4][16][2];
  int tid = threadIdx.x;
  int lane = tid & 63, wid = tid >> 6;
  int quad = lane >> 4, l16 = lane & 15;
  int wm = wid >> 2, wn = wid & 3;
  int blk = blockIdx.x;

  f4v acc[9];
#pragma unroll
  for (int i = 0; i < 9; i++) acc[i] = (f4v){0.f, 0.f, 0.f, 0.f};

  int arow = tid >> 4;
  int acp  = tid & 15;
  int r = blk * 64 + arow;
  const float* aptr;
  if (amode == 0){ int t = r >> 7, b = r & 127; aptr = A + ((size_t)(b * TT + t)) * II + acp * 2; }
  else           { aptr = A + (size_t)r * DD + acp * 2; }

  for (int ks = 0; ks < ksteps; ks++){
    __syncthreads();
    float2 a2 = *(const float2*)(aptr + ks * 32);
    uint pk = (uint)f2bf(a2.x) | ((uint)f2bf(a2.y) << 16);
    *(uint*)&As[arow][acp * 2] = pk;
    __syncthreads();
    s8v af = *(const s8v*)&As[wm * 16 + l16][quad * 8];
    int kc = ks * 4 + quad;
    const s8v* bp = (const s8v*)Bpk + (size_t)kc * (NT * 16) + l16;
#pragma unroll
    for (int i = 0; i < 9; i++){
      s8v bf = bp[(wn * 9 + i) * 16];
      acc[i] = __builtin_amdgcn_mfma_f32_16x16x32_bf16(af, bf, acc[i], 0, 0, 0);
    }
  }

  int rowbase = blk * 64 + wm * 16 + quad * 4;
  if (do_ln){
    float s1[4], s2[4];
#pragma unroll
    for (int g = 0; g < 4; g++){
      float a = 0.f, q = 0.f;
#pragma unroll
      for (int i = 0; i < 9; i++){ float v = acc[i][g]; a += v; q += v * v; }
#pragma unroll
      for (int m = 1; m < 16; m <<= 1){ a += __shfl_xor(a, m, 64); q += __shfl_xor(q, m, 64); }
      s1[g] = a; s2[g] = q;
    }
    if (l16 == 0){
#pragma unroll
      for (int g = 0; g < 4; g++){
        red[wm][wn][quad * 4 + g][0] = s1[g];
        red[wm][wn][quad * 4 + g][1] = s2[g];
      }
    }
    __syncthreads();
#pragma unroll
    for (int g = 0; g < 4; g++){
      int rr = quad * 4 + g;
      float S1 = red[wm][0][rr][0] + red[wm][1][rr][0] + red[wm][2][rr][0] + red[wm][3][rr][0];
      float S2 = red[wm][0][rr][1] + red[wm][1][rr][1] + red[wm][2][rr][1] + red[wm][3][rr][1];
      float mean = S1 * (1.f / 513.f);
      float var  = S2 * (1.f / 513.f) - mean * mean;
      float inv  = 1.f / (sqrtf(var + EPSL) + EPSL);
      size_t rg = (size_t)(rowbase + g);
#pragma unroll
      for (int i = 0; i < 9; i++){
        int n = wn * 144 + i * 16 + l16;
        if (n < NC){
          float val = gam[n] * ((acc[i][g] - mean) * inv) + bet[n] + bias[n];
          out[rg * NPAD + n] = f2bf(val);
        }
      }
    }
  } else {
#pragma unroll
    for (int g = 0; g < 4; g++){
      size_t rg = (size_t)(rowbase + g);
#pragma unroll
      for (int i = 0; i < 9; i++){
        int n = wn * 144 + i * 16 + l16;
        if (n < NC) out[rg * NPAD + n] = f2bf(acc[i][g]);
      }
    }
  }
}

// ---------------- per-batch-row sequential recurrence, COLUMN-SPLIT x2 ------
// grid = 256 blocks (<= #CUs, so all co-resident -> flag sync is deadlock-free).
// block bid: c = bid>>7 (column half), b = bid&127 (batch row).
// 1024 threads = 16 waves. Block owns v/h columns [c*256, c*256+256); c==1 also col 512.
// Per step: one v-vector exchange with partner block via L2/L3 (relaxed agent
// atomics, release flag), redundant identical LN-stats/gates/tanh in both blocks,
// GEMV y = tanh . U_hi on the matrix pipe (16 reg-prefetched fragments/thread).
__global__ __launch_bounds__(1024, 4) void rnn_layer(
    int layer,
    const float* __restrict__ x,
    float* __restrict__ h_seq,
    const ushort* __restrict__ lnXW,
    ushort* __restrict__ vbuf,
    const float* __restrict__ fkRd, const float* __restrict__ hvRd,
    float* __restrict__ fkWr, float* __restrict__ hvWr,
    const ushort* __restrict__ Upk2,
    const float* __restrict__ U,
    const int* __restrict__ mask,
    const float* __restrict__ gam1, const float* __restrict__ bet1,
    const float* __restrict__ bias,
    float* __restrict__ out,
    float* __restrict__ xch,
    int* __restrict__ flags)
{
  __shared__ __align__(16) ushort tanh16[512];  // f16 tanh (GEMV A operand)
  __shared__ __align__(16) float  tanhvf[512];  // f32 tanh (h update)
  __shared__ float yld[256];
  __shared__ float red_a[16], red_q[16], red_p[16];

  int tid = threadIdx.x;            // 0..1023
  int bid = blockIdx.x;             // 0..255
  int c   = bid >> 7;
  int b   = bid & 127;
  int lane = tid & 63, wid = tid >> 6;   // wid 0..15
  int quad = lane >> 4, l16 = lane & 15;
  const bool lastL = (layer == 3);
  int nt = c * 16 + wid;            // this wave's global 16-col tile

  // persistent per-thread state
  float sv = 0.f;                   // owners (tid<256): v[c*256+tid]
  float v5 = 0.f;                   // tid==512 on c==1: v[512]
  float h_lo = 0.f, h_hi = 0.f;     // owners
  float fk_c = 0.f, hv_c = 0.f;     // gate carries (all threads, identical)

  float g1n = (tid < 512) ? gam1[tid] : 0.f;
  float b1n = (tid < 512) ? bet1[tid] : 0.f;
  float g10 = gam1[0], b10 = bet1[0];
  float g1e = gam1[512], b1e = bet1[512];
  float bias0 = bias[0];
  float uc = (tid < 512) ? U[(size_t)(II + tid) * NC + 512] : 0.f;  // col-512 U column (f32)

  int gcol = c * 256 + tid;         // owners' global column (valid for tid<256)
  int* pflag = flags + ((c ^ 1) * BB + b);   // partner's flag
  int* mflag = flags + (c * BB + b);         // my flag

  for (int t = 0; t < TT; t++){
    size_t row = (size_t)(t * BB + b);
    int par = t & 1;

    // ---- P0: register-prefetch this step's U fragments (independent of all state)
    h8v ufr[16];
    {
      const h8v* Ub = (const h8v*)Upk2 + ((size_t)quad * NT2 + nt) * 16 + l16;
#pragma unroll
      for (int ks = 0; ks < 16; ks++) ufr[ks] = Ub[(size_t)ks * (4 * NT2 * 16)];
    }

    // ---- P0b: stream loads for this step
    int   mraw  = mask[b * TT + t];
    int   mprev = (t > 0) ? mask[b * TT + t - 1] : 0;
    float lw    = (tid < 512) ? bf2f(lnXW[row * NPAD + tid]) : 0.f;
    float lw0   = bf2f(lnXW[row * NPAD]);
    float lw512 = (tid == 0) ? bf2f(lnXW[row * NPAD + 512]) : 0.f;
    float fkp_tm1 = 0.f, fkp = 0.f, hvp = 1.f;
    if (layer > 0){
      fkp_tm1 = fkRd[t * BB + b];
      fkp = (t + 1 < TT) ? fkRd[(t + 1) * BB + b] : 0.f;
      hvp = hvRd[t * BB + b];
    }
    float xu = 0.f, xlo = 0.f, xhi = 0.f;
    if (tid < 256){
      xu = bf2f(vbuf[row * NPAD + gcol]);
      if (layer == 0){ xlo = x[((size_t)(b * TT + t)) * II + gcol]; xhi = 0.f; }
      else { xlo = h_seq[row * DD + gcol]; xhi = h_seq[row * DD + 512 + gcol]; }
    }
    float xu5 = (tid == 512) ? bf2f(vbuf[row * NPAD + 512]) : 0.f;

    // ---- P1: sync with partner, fetch v vector (coherence-point loads)
    float vk = 0.f, vv5 = 0.f, v0 = 0.f;
    if (t > 0){
      if (tid == 0){
        int target = layer * TT + t;
        while (__hip_atomic_load(pflag, __ATOMIC_RELAXED, __HIP_MEMORY_SCOPE_AGENT) < target)
          __builtin_amdgcn_s_sleep(1);
      }
      __syncthreads();   // B1: partner's step-t v state is published
      float* xr = xch + ((size_t)par * BB + b) * XST;
      if (tid < 512) vk = __hip_atomic_load(xr + tid, __ATOMIC_RELAXED, __HIP_MEMORY_SCOPE_AGENT);
      if (tid == 0 || tid == 512)
        vv5 = __hip_atomic_load(xr + 512, __ATOMIC_RELAXED, __HIP_MEMORY_SCOPE_AGENT);
      v0 = __hip_atomic_load(xr, __ATOMIC_RELAXED, __HIP_MEMORY_SCOPE_AGENT);
    }

    // ---- P2: LN stats over 513 entries (threads 0..511 = v[k], thread 512 = v[512])
    {
      float a = (tid < 512) ? vk : ((tid == 512) ? vv5 : 0.f);
      float q = a * a;
#pragma unroll
      for (int m = 1; m < 64; m <<= 1){ a += __shfl_xor(a, m, 64); q += __shfl_xor(q, m, 64); }
      if (lane == 0){ red_a[wid] = a; red_q[wid] = q; }
    }
    __syncthreads();     // B2
    float S = 0.f, Q = 0.f;
#pragma unroll
    for (int w = 0; w < 16; w++){ S += red_a[w]; Q += red_q[w]; }
    float mean = S * (1.f / 513.f);
    float var  = Q * (1.f / 513.f) - mean * mean;
    float inv  = 1.f / (sqrtf(var + EPSL) + EPSL);

    // ---- P3: gate scalars (redundant, identical on all threads) + tanh
    bool mk  = mraw > 0;
    bool mk2 = (t > 0) && (mprev > 0) && !mk;
    float sum20 = (v0 - mean) * inv * g10 + b10;
    float s0 = lw0 + sum20;
    float fk_both = hsig(s0);
    float fk_t1   = hsig(sum20 + bias0);
    float fk = fkp_tm1 + (1.f - fkp_tm1) * (fk_c * fk_both + (1.f - fk_c) * fk_t1);
    if (mk2) fk = 0.f;
    float h_only = hv_c * fk * (fkp + (1.f - fkp) * (1.f - hvp));
    float x_only = hvp * (1.f - fkp) * (1.f - fk + fk * (1.f - hv_c));
    float both   = (1.f - fkp) * fk * hv_c * hvp;
    float hv = 1.f - (1.f - h_only) * (1.f - x_only) * (1.f - both);
    float fk_new = mk ? fk : fk_c;
    float hv_new = mk ? hv : hv_c;
    if (mk2) fk_new = 0.f;
    fk_c = fk_new; hv_c = hv_new;
    if (tid == 0 && c == 0 && !lastL){
      fkWr[t * BB + b] = fk_new;
      hvWr[t * BB + b] = hv_new;
    }

    if (tid < 512){
      float sum2 = (vk - mean) * inv * g1n + b1n;
      float s = lw + sum2;
      float th = tanhf(s);
      if (tid == 0){
        float sum2e = (vv5 - mean) * inv * g1e + b1e;
        float the = tanhf(lw512 + sum2e);
        tanh16[511] = __builtin_bit_cast(ushort, (_Float16)the);
        tanhvf[511] = the;
      } else {
        tanh16[tid - 1] = __builtin_bit_cast(ushort, (_Float16)th);
        tanhvf[tid - 1] = th;
      }
    }
    __syncthreads();     // B3: tanh visible

    // ---- P4: GEMV on matrix pipe (own 256 cols) + col-512 dot on VALU
    {
      f4v acc = (f4v){0.f, 0.f, 0.f, 0.f};
#pragma unroll
      for (int ks = 0; ks < 16; ks++){
        h8v af = *(const h8v*)&tanh16[ks * 32 + quad * 8];  // broadcast A rows
        acc = __builtin_amdgcn_mfma_f32_16x16x32_f16(af, ufr[ks], acc, 0, 0, 0);
      }
      if (lane < 16) yld[wid * 16 + lane] = acc[0];
    }
    {
      float p = (tid < 512) ? tanhvf[tid] * uc : 0.f;
#pragma unroll
      for (int m = 1; m < 64; m <<= 1) p += __shfl_xor(p, m, 64);
      if (lane == 0) red_p[wid] = p;
    }
    __syncthreads();     // B4: y ready

    // ---- P5: state updates + publish v for next step
    float* xw = xch + ((size_t)((t + 1) & 1) * BB + b) * XST;
    if (tid < 256){
      float y = yld[tid];
      float nv = h_only * sv + x_only * xu + both * y;
      if (mk) sv = nv;
      __hip_atomic_store(xw + gcol, sv, __ATOMIC_RELAXED, __HIP_MEMORY_SCOPE_AGENT);
      if (!lastL) vbuf[row * NPAD + gcol] = f2bf(sv);
      float thh = tanhvf[gcol];
      float nh_lo = h_only * h_lo + x_only * xlo;
      float nh_hi = h_only * h_hi + x_only * xhi + both * thh;
      if (mk){ h_lo = nh_lo; h_hi = nh_hi; }
      if (!lastL){
        h_seq[row * DD + gcol] = h_lo;
        h_seq[row * DD + 512 + gcol] = h_hi;
      }
      if (lastL && t == TT - 1) out[b * HH + gcol] = h_hi;
    }
    if (tid == 512 && c == 1){
      float y512 = 0.f;
#pragma unroll
      for (int w = 0; w < 16; w++) y512 += red_p[w];
      float nv5 = h_only * v5 + x_only * xu5 + both * y512;
      if (mk) v5 = nv5;
      __hip_atomic_store(xw + 512, v5, __ATOMIC_RELAXED, __HIP_MEMORY_SCOPE_AGENT);
      if (!lastL) vbuf[row * NPAD + 512] = f2bf(v5);
    }
    __syncthreads();     // B5: all publishes issued & drained (vmcnt at barrier)
    if (tid == 0)
      __hip_atomic_store(mflag, layer * TT + t + 1, __ATOMIC_RELEASE, __HIP_MEMORY_SCOPE_AGENT);
  }
}

extern "C" void kernel_launch(void* const* d_in, const int* in_sizes, int n_in,
                              void* d_out, int out_size, void* d_ws, size_t ws_size,
                              hipStream_t stream)
{
  (void)in_sizes; (void)n_in; (void)out_size; (void)ws_size;
  const float* x      = (const float*)d_in[0];
  const int*   mask   = (const int*)d_in[1];
  const float* W      = (const float*)d_in[2];
  const float* U      = (const float*)d_in[3];
  const float* bias   = (const float*)d_in[4];
  const float* gammas = (const float*)d_in[5];
  const float* betas  = (const float*)d_in[6];
  float* out = (float*)d_out;

  char* ws = (char*)d_ws;
  size_t off = 0;
  auto alloc = [&](size_t bytes) -> void* {
    void* p = ws + off;
    off += (bytes + 255) & ~(size_t)255;
    return p;
  };
  float*  h_seq = (float*) alloc((size_t)TT * BB * DD * 4);
  ushort* lnXW  = (ushort*)alloc((size_t)TT * BB * NPAD * 2);
  ushort* vbuf  = (ushort*)alloc((size_t)TT * BB * NPAD * 2);
  float*  fkbuf = (float*) alloc((size_t)2 * TT * BB * 4);   // layer-parity double buffer
  float*  hvbuf = (float*) alloc((size_t)2 * TT * BB * 4);
  ushort* Wpk   = (ushort*)alloc((size_t)128 * NT * 16 * 8 * 2);
  ushort* Upk   = (ushort*)alloc((size_t)128 * NT * 16 * 8 * 2);
  ushort* Upk2  = (ushort*)alloc((size_t)64 * NT2 * 16 * 8 * 2);
  float*  xch   = (float*) alloc((size_t)2 * BB * XST * 4);  // v exchange, parity x batch
  int*    flags = (int*)   alloc((size_t)2 * BB * 4);

  hipMemsetAsync(flags, 0, (size_t)2 * BB * 4, stream);

  int npk = 128 * NT * 16 * 8;
  prepack_B<<<dim3((npk + 255) / 256), dim3(256), 0, stream>>>(W, Wpk);
  prepack_B<<<dim3((npk + 255) / 256), dim3(256), 0, stream>>>(U, Upk);
  int npk2 = 64 * NT2 * 16 * 8;
  prepack_Uhi_f16<<<dim3((npk2 + 255) / 256), dim3(256), 0, stream>>>(U, Upk2);

  const float* g0 = gammas,      *g1 = gammas + NC;
  const float* be0 = betas,      *be1 = betas + NC;

  // layer 0: lnXW = LN(x @ W_lo)+b ; vbuf = x @ U_lo (raw)
  gemm_ln<<<dim3(256), dim3(1024), 0, stream>>>(x, 0, 16, Wpk, lnXW, 1, g0, be0, bias);
  gemm_ln<<<dim3(256), dim3(1024), 0, stream>>>(x, 0, 16, Upk, vbuf, 0, g0, be0, bias);

  for (int d = 0; d < 4; d++){
    if (d > 0)
      gemm_ln<<<dim3(256), dim3(1024), 0, stream>>>(h_seq, 1, 32, Wpk, lnXW, 1, g0, be0, bias);
    const float* fkRd = fkbuf + ((size_t)((d + 1) & 1)) * TT * BB;
    const float* hvRd = hvbuf + ((size_t)((d + 1) & 1)) * TT * BB;
    float* fkWr = fkbuf + ((size_t)(d & 1)) * TT * BB;
    float* hvWr = hvbuf + ((size_t)(d & 1)) * TT * BB;
    rnn_layer<<<dim3(256), dim3(1024), 0, stream>>>(d, x, h_seq, lnXW, vbuf,
                                                    fkRd, hvRd, fkWr, hvWr,
                                                    Upk2, U, mask, g1, be1, bias, out,
                                                    xch, flags);
  }
}